// Round 10
// baseline (98.139 us; speedup 1.0000x reference)
//
#include <hip/hip_runtime.h>

typedef _Float16 half8 __attribute__((ext_vector_type(8)));
typedef float f16v __attribute__((ext_vector_type(16)));
typedef float f4 __attribute__((ext_vector_type(4)));
typedef unsigned long long ull;

#define X_SLAB   1048576            // 32^4
#define PLANE_BYTES (34*36*4*2)     // 9792: one (j1,j2) plane [j3<34][j4<36][t<4] f16
#define RPT_SITES (34*34*34*36)     // 1,414,944 sites (8B each)
#define RPT_OFF  65536              // byte offset of rp_t in ws (tab before it)
#define RPT_SLACK 4096              // covers stage-window overrun past last plane
#define MSK_OFF  (RPT_OFF + RPT_SITES*8 + RPT_SLACK)   // 1MB mask nibbles
#define TAB_N    (3*6*3*512)        // 27648 f16 entries
#define TAB_ELEMS  (4*81*8)         // fp32 fallback table

// ---------------------------------------------------------------------------
// prep: (a) t-innermost padded relu f16 array rpt (as R7/R9);
//       (b) mask nibble per interior point: mskb[pt] bit t = (x[t][pt] != 0)
//           (computed from pre-relu values) -- conv never touches x again;
//       (c) block 0 builds the d2-packed MFMA B table.
// ---------------------------------------------------------------------------
__global__ __launch_bounds__(256)
void prep(const float* __restrict__ x, const float* __restrict__ w,
          ull* __restrict__ rpt, unsigned char* __restrict__ mskb,
          _Float16* __restrict__ tabm) {
    unsigned s = blockIdx.x * 256 + threadIdx.x;
    if (s < RPT_SITES) {
        unsigned q = s;
        int j4 = q % 36; q /= 36;
        int j3 = q % 34; q /= 34;
        int j2 = q % 34; q /= 34;
        int j1 = q;
        union { _Float16 h[4]; ull u; } pk;
        pk.u = 0ull;
        if (j1 >= 1 && j1 <= 32 && j2 >= 1 && j2 <= 32 &&
            j3 >= 1 && j3 <= 32 && j4 >= 1 && j4 <= 32) {
            size_t off = (size_t)(j1-1)*32768 + (j2-1)*1024 + (j3-1)*32 + (j4-1);
            unsigned nib = 0;
            #pragma unroll
            for (int t = 0; t < 4; ++t) {
                float v = x[(size_t)t*X_SLAB + off];
                nib |= (v != 0.f ? 1u : 0u) << t;
                pk.h[t] = (_Float16)fmaxf(v, 0.f);
            }
            mskb[off] = (unsigned char)nib;
        }
        rpt[s] = pk.u;
    }
    if (blockIdx.x == 0) {
        for (int idx = threadIdx.x; idx < TAB_N; idx += 256) {
            int j = idx & 7, l = (idx >> 3) & 63, slice = idx >> 9;   // slice<54
            int p4 = slice % 3, j2rel = (slice/3) % 6, p2 = slice/18;
            int n32 = l & 31;
            int d2 = n32 >> 3, n8 = n32 & 7;
            int k = 8*(l>>5) + j;
            int p5h = k >> 2, t = k & 3;
            int p3 = j2rel - d2;
            float val = 0.f;
            if (p5h < 3 && p3 >= 0 && p3 <= 2) {
                int br = n8 & 1, sc = n8 >> 1, s1 = sc >> 1, s2 = sc & 1;
                int t1 = t >> 1, t2 = t & 1;
                int a = t1 - s1 + 1, b = t2 - s2 + 1;
                int widx = (br == 0)
                    ? (a*243 + b*81 + p2*27 + p3*9 + p4*3 + p5h)
                    : (b*243 + a*81 + p4*27 + p5h*9 + p2*3 + p3);
                val = w[widx];
            }
            tabm[idx] = (_Float16)val;
        }
    }
}

// ---------------------------------------------------------------------------
// conv_mfma: fully barrier-free per-wave async pipeline, 4 waves/SIMD.
// Grid (8,32,4): block = (e2b=4bx, e1, 8 e3-rows). Wave wv owns 2 e3-rows
// (window rows R..R+3, 1.5KB useful staged as 2x1KB lane*16 DMA), depth-2
// LDS double buffer, s_waitcnt vmcnt(5) keeps next stage+B in flight.
// Queue entering compute: [s(it)x2,B(it)x3,s(nit)x2,B(nit)x3] -> vmcnt(5).
// Epilogue reads mask nibbles straight from global (L2-hot, 1MB total).
// ---------------------------------------------------------------------------
__global__ __launch_bounds__(256)
void conv_mfma(const ull* __restrict__ rpt, const unsigned char* __restrict__ mskb,
               const _Float16* __restrict__ tabm, float* __restrict__ out) {
    __shared__ __align__(16) unsigned char stg[4][2][2048];   // per-wave dbuf

    const int tid  = threadIdx.x;
    const int lane = tid & 63;
    const int wv   = tid >> 6;                     // 0..3
    const int e2b  = blockIdx.x * 4;
    const int e1   = blockIdx.y;
    const int bz   = blockIdx.z;                   // e3 eighth (8 rows)

    f16v acc[2];
    #pragma unroll
    for (int r = 0; r < 2; ++r)
        #pragma unroll
        for (int i = 0; i < 16; ++i) acc[r][i] = 0.f;

    const int R     = bz*8 + wv*2;                     // window rows R..R+3
    const int j4off = (lane & 31)*8 + (lane >> 5)*16;  // A-frag byte offset in row
    const char* aglob0 = (const char*)rpt + (size_t)R*288 + lane*16;

    auto stage_to = [&](int it, int slot) {
        int p2 = it / 6, j2 = it - p2*6;
        const char* src = aglob0 + ((size_t)(e1+p2)*34 + (e2b+j2))*PLANE_BYTES;
        unsigned char* dst = &stg[wv][slot][0] + lane*16;
        #pragma unroll
        for (int k = 0; k < 2; ++k)
            __builtin_amdgcn_global_load_lds(
                (const __attribute__((address_space(1))) unsigned int*)(src + k*1024),
                (__attribute__((address_space(3))) unsigned int*)(dst + k*1024),
                16, 0, 0);
    };
    auto loadB = [&](int it, half8* B) {
        const _Float16* tb = tabm + it*1536 + lane*8;
        B[0] = *(const half8*)(tb);
        B[1] = *(const half8*)(tb + 512);
        B[2] = *(const half8*)(tb + 1024);
    };
    auto compute = [&](int slot, const half8* B) {
        const unsigned char* sb = &stg[wv][slot][0];
        union { ull u[2]; half8 h; } A[4];
        #pragma unroll
        for (int j3l = 0; j3l < 4; ++j3l) {
            const ull* ap = (const ull*)(sb + j3l*288 + j4off);
            A[j3l].u[0] = ap[0];
            A[j3l].u[1] = ap[1];
        }
        #pragma unroll
        for (int p4 = 0; p4 < 3; ++p4) {
            acc[0] = __builtin_amdgcn_mfma_f32_32x32x16_f16(A[p4  ].h, B[p4], acc[0], 0,0,0);
            acc[1] = __builtin_amdgcn_mfma_f32_32x32x16_f16(A[p4+1].h, B[p4], acc[1], 0,0,0);
        }
    };

    half8 Ba[3], Bb[3];
    stage_to(0, 0);
    loadB(0, Ba);

    #pragma unroll 1
    for (int ip = 0; ip < 9; ++ip) {
        const int itE = 2*ip;
        {   // even: consume slot0/Ba, prefetch itE+1 -> slot1/Bb
            stage_to(itE + 1, 1);
            loadB(itE + 1, Bb);
            asm volatile("s_waitcnt vmcnt(5)" ::: "memory");
            compute(0, Ba);
        }
        {   // odd: consume slot1/Bb, prefetch itE+2 (dummy 17 at tail) -> slot0/Ba
            int nit = (itE + 2 < 18) ? itE + 2 : 17;
            stage_to(nit, 0);
            loadB(nit, Ba);
            asm volatile("s_waitcnt vmcnt(5)" ::: "memory");
            compute(1, Bb);
        }
    }

    // ---- epilogue ----
    // D layout: col n32 = lane&31 (d2 = n32>>3, n8 = n32&7),
    // row m(e4) = (reg&3) + 8*(reg>>2) + 4*(lane>>5)
    const int n8 = lane & 7;
    const int d2 = (lane >> 3) & 3;
    const int h  = lane >> 5;
    const int sbit = n8 >> 1;
    const size_t colbase = (size_t)e1*32768 + (size_t)(e2b + d2)*1024;
    #pragma unroll
    for (int rloc = 0; rloc < 2; ++rloc) {
        const int e3 = R + rloc;
        float v[16];
        #pragma unroll
        for (int g = 0; g < 4; ++g) {
            unsigned mw = *(const unsigned*)&mskb[colbase + e3*32 + 8*g + 4*h];
            #pragma unroll
            for (int j = 0; j < 4; ++j) {
                float a  = acc[rloc][4*g + j];
                float sg = __builtin_amdgcn_rcpf(1.f + __expf(-a));
                v[4*g+j] = ((mw >> (8*j + sbit)) & 1u) ? sg : 0.f;
            }
        }
        #pragma unroll
        for (int i = 0; i < 16; ++i) {
            v[i] += __shfl_xor(v[i], 1);
            v[i] += __shfl_xor(v[i], 2);
            v[i] += __shfl_xor(v[i], 4);
        }
        if (n8 == 0) {
            #pragma unroll
            for (int g = 0; g < 4; ++g) {
                f4 o; o.x = v[4*g]; o.y = v[4*g+1]; o.z = v[4*g+2]; o.w = v[4*g+3];
                *(f4*)(out + colbase + e3*32 + 8*g + 4*h) = o;
            }
        }
    }
}

// ---------------------------------------------------------------------------
// fp32 fallback (ws too small): known-good from round 1.
// ---------------------------------------------------------------------------
__global__ void build_wtab(const float* __restrict__ w, float* __restrict__ tab) {
    int idx = blockIdx.x * blockDim.x + threadIdx.x;
    if (idx >= TAB_ELEMS) return;
    int n  = idx & 7;
    int r  = idx >> 3;
    int p5 = r % 3; r /= 3;
    int p4 = r % 3; r /= 3;
    int p3 = r % 3; r /= 3;
    int p2 = r % 3; r /= 3;
    int t  = r;
    int t1 = t >> 1, t2 = t & 1;
    int br = n & 1;
    int s  = n >> 1;
    int s1 = s >> 1, s2 = s & 1;
    int a = t1 - s1 + 1;
    int b = t2 - s2 + 1;
    int widx = (br == 0)
        ? (a*243 + b*81 + p2*27 + p3*9 + p4*3 + p5)
        : (b*243 + a*81 + p4*27 + p5*9 + p2*3 + p3);
    tab[idx] = w[widx];
}

__global__ __launch_bounds__(256)
void conv_fp32(const float* __restrict__ x,
               const float* __restrict__ tab,
               float* __restrict__ out) {
    const int e4 = threadIdx.x;
    const int e3 = blockIdx.x * 8 + threadIdx.y;
    const int e2 = blockIdx.y;
    const int e1 = blockIdx.z;

    float acc[8];
    #pragma unroll
    for (int n = 0; n < 8; ++n) acc[n] = 0.f;

    #pragma unroll 1
    for (int t = 0; t < 4; ++t) {
        const float* st  = x + (size_t)t * X_SLAB;
        const float* wt0 = tab + t * 648;
        #pragma unroll
        for (int p2 = 0; p2 < 3; ++p2) {
            #pragma unroll
            for (int p3 = 0; p3 < 3; ++p3) {
                int i1 = e1 + p2 - 1, i2 = e2 + p3 - 1;
                bool v12 = ((unsigned)i1 < 32u) && ((unsigned)i2 < 32u);
                const float* base = st + (i1*32768 + i2*1024 + (e3-1)*32 + (e4-1));
                const float* wt = wt0 + (p2*3 + p3) * 72;
                #pragma unroll
                for (int p4 = 0; p4 < 3; ++p4) {
                    int i3 = e3 + p4 - 1;
                    bool v3 = v12 && ((unsigned)i3 < 32u);
                    #pragma unroll
                    for (int p5 = 0; p5 < 3; ++p5) {
                        int i4 = e4 + p5 - 1;
                        bool ok = v3 && ((unsigned)i4 < 32u);
                        float v = ok ? fmaxf(base[p4*32 + p5], 0.f) : 0.f;
                        const float* w8 = wt + (p4*3 + p5)*8;
                        #pragma unroll
                        for (int n = 0; n < 8; ++n)
                            acc[n] = fmaf(w8[n], v, acc[n]);
                    }
                }
            }
        }
    }

    const size_t eflat = (size_t)e1*32768 + e2*1024 + e3*32 + e4;
    float res = 0.f;
    #pragma unroll
    for (int i = 0; i < 4; ++i) {
        float xv = x[(size_t)i * X_SLAB + eflat];
        float s0 = __builtin_amdgcn_rcpf(1.f + __expf(-acc[2*i]));
        float s1 = __builtin_amdgcn_rcpf(1.f + __expf(-acc[2*i+1]));
        float m  = (xv != 0.f) ? 1.f : 0.f;
        res = fmaf(m, s0 + s1, res);
    }
    out[eflat] = res;
}

// ---------------------------------------------------------------------------
extern "C" void kernel_launch(void* const* d_in, const int* in_sizes, int n_in,
                              void* d_out, int out_size, void* d_ws, size_t ws_size,
                              hipStream_t stream) {
    const float* x = (const float*)d_in[0];    // (1,2,2,32,32,32,32) fp32
    const float* w = (const float*)d_in[1];    // (729,) fp32
    float* out = (float*)d_out;                // (1,32,32,32,32) fp32

    const size_t need = (size_t)MSK_OFF + (size_t)X_SLAB;  // rpt + slack + 1MB mask

    if (ws_size >= need) {
        _Float16*      tabm = (_Float16*)d_ws;                 // 55296 B @ 0
        ull*           rpt  = (ull*)((char*)d_ws + RPT_OFF);
        unsigned char* mskb = (unsigned char*)d_ws + MSK_OFF;
        prep<<<dim3((RPT_SITES + 255)/256), dim3(256), 0, stream>>>(x, w, rpt, mskb, tabm);
        dim3 grd(8, 32, 4), blk(256, 1, 1);
        conv_mfma<<<grd, blk, 0, stream>>>(rpt, mskb, tabm, out);
    } else {
        float* tab = (float*)d_ws;
        build_wtab<<<dim3((TAB_ELEMS + 255)/256), dim3(256), 0, stream>>>(w, tab);
        dim3 blk(32, 8, 1), grd(4, 32, 32);
        conv_fp32<<<grd, blk, 0, stream>>>(x, tab, out);
    }
}